// Round 2
// baseline (319.012 us; speedup 1.0000x reference)
//
#include <hip/hip_runtime.h>

// ---------------- constants ----------------
#define BATCH   2
#define NSEQ    2048
#define DMODEL  1024
#define HEADS   16
#define DHEAD   64
#define INNER   1024      // HEADS*DHEAD
#define NCOL    3072      // 3*INNER
#define BNROWS  4096      // BATCH*NSEQ
#define KDIM    1024      // contraction dim for both GEMMs

typedef unsigned short ushort;
typedef unsigned int   uint;
typedef __attribute__((ext_vector_type(8))) short  short8;
typedef __attribute__((ext_vector_type(4))) float  f32x4;
typedef __attribute__((ext_vector_type(8))) ushort ushort8;
typedef __attribute__((ext_vector_type(4))) float  f4v;

// SCALE * log2(e) so softmax can use exp2 directly
#define QSCALE 0.1803368801111204f   // 64^-0.5 * 1.4426950408889634

__device__ __forceinline__ ushort f2bf(float f) {
  uint u = __builtin_bit_cast(uint, f);
  u += 0x7fffu + ((u >> 16) & 1u);   // RNE
  return (ushort)(u >> 16);
}

__device__ __forceinline__ f32x4 mfma16(short8 a, short8 b, f32x4 c) {
  return __builtin_amdgcn_mfma_f32_16x16x32_bf16(a, b, c, 0, 0, 0);
}

#define GLDS(gp, lp) __builtin_amdgcn_global_load_lds( \
    (const __attribute__((address_space(1))) void*)(gp), \
    (__attribute__((address_space(3))) void*)(lp), 16, 0, 0)

// ---------------- lengths from mask (int32 0/1) ----------------
__global__ __launch_bounds__(256) void lens_kernel(const int* __restrict__ mask,
                                                   int* __restrict__ lens) {
  __shared__ int sm[256];
  int b = blockIdx.x, t = threadIdx.x;
  int s = 0;
  for (int i = t; i < NSEQ; i += 256) s += (mask[b * NSEQ + i] != 0);
  sm[t] = s;
  __syncthreads();
  for (int off = 128; off > 0; off >>= 1) {
    if (t < off) sm[t] += sm[t + off];
    __syncthreads();
  }
  if (t == 0) lens[b] = sm[0];
}

// ---------------- fp32 -> bf16 cast (vectorized) ----------------
__global__ __launch_bounds__(256) void cast_bf16_kernel(const float* __restrict__ x,
                                                        ushort* __restrict__ y, int n8) {
  int i = blockIdx.x * 256 + threadIdx.x;
  if (i >= n8) return;
  const f4v* xv = (const f4v*)x;
  f4v a = xv[(size_t)i * 2], b = xv[(size_t)i * 2 + 1];
  ushort8 o;
  o[0] = f2bf(a[0]); o[1] = f2bf(a[1]); o[2] = f2bf(a[2]); o[3] = f2bf(a[3]);
  o[4] = f2bf(b[0]); o[5] = f2bf(b[1]); o[6] = f2bf(b[2]); o[7] = f2bf(b[3]);
  ((ushort8*)y)[i] = o;
}

// ---------------- fp32 (K,C) -> bf16 transposed (C,K) ----------------
__global__ __launch_bounds__(256) void transpose_bf16_kernel(const float* __restrict__ W,
                                                             ushort* __restrict__ Wt,
                                                             int K, int C) {
  __shared__ float tile[32][33];
  int c0 = blockIdx.x * 32, k0 = blockIdx.y * 32;
  int tx = threadIdx.x, ty = threadIdx.y;   // (32,8)
#pragma unroll
  for (int i = 0; i < 4; ++i)
    tile[ty + i * 8][tx] = W[(size_t)(k0 + ty + i * 8) * C + c0 + tx];
  __syncthreads();
#pragma unroll
  for (int i = 0; i < 4; ++i)
    Wt[(size_t)(c0 + ty + i * 8) * K + k0 + tx] = f2bf(tile[tx][ty + i * 8]);
}

// ---------------- bf16 (bh, n, d) -> (bh, d, n) transpose for V ----------------
__global__ __launch_bounds__(256) void vtrans_kernel(const ushort* __restrict__ v,
                                                     ushort* __restrict__ vt) {
  __shared__ ushort t[32][34];   // +2 pad: row stride 68B spreads banks
  int d0 = blockIdx.x * 32, n0 = blockIdx.y * 32, bh = blockIdx.z;
  const ushort* vb  = v  + (size_t)bh * NSEQ * DHEAD;
  ushort*       vtb = vt + (size_t)bh * NSEQ * DHEAD;
  int tx = threadIdx.x, ty = threadIdx.y;   // (32,8)
#pragma unroll
  for (int i = 0; i < 4; ++i)
    t[ty + i * 8][tx] = vb[(size_t)(n0 + ty + i * 8) * DHEAD + d0 + tx];
  __syncthreads();
#pragma unroll
  for (int i = 0; i < 4; ++i)
    vtb[(size_t)(d0 + ty + i * 8) * NSEQ + n0 + tx] = t[tx][ty + i * 8];
}

// ---------------- m97-style bf16 GEMM, C = A(M,K) @ Bt(N,K)^T ----------------
// 128x128 tile, BK=64, 4 waves (2x2), 4x4 16x16 frags per wave.
// EPI 0: QKV epilogue (scatter q*QSCALE, k, v as bf16 into (bh,n,d))
// EPI 1: out-proj epilogue (+bias, fp32 store)
template <int EPI>
__global__ __launch_bounds__(256) void gemm_bt_kernel(
    const ushort* __restrict__ A, const ushort* __restrict__ Bt,
    ushort* __restrict__ q_out, ushort* __restrict__ k_out, ushort* __restrict__ v_out,
    const float* __restrict__ bias, float* __restrict__ outp) {
  __shared__ __align__(16) ushort lA[128 * 64];
  __shared__ __align__(16) ushort lB[128 * 64];
  const int tid = threadIdx.x;
  const int wv = tid >> 6, lane = tid & 63;
  const int wr = wv >> 1, wc = wv & 1;
  const int m0 = blockIdx.x * 128, n0 = blockIdx.y * 128;
  const int l15 = lane & 15, l4 = lane >> 4;

  f32x4 zero = {0.f, 0.f, 0.f, 0.f};
  f32x4 acc[4][4];
#pragma unroll
  for (int i = 0; i < 4; ++i)
#pragma unroll
    for (int j = 0; j < 4; ++j) acc[i][j] = zero;

  const char* Ab  = (const char*)A;
  const char* Bb  = (const char*)Bt;
  char* lAb = (char*)lA;
  char* lBb = (char*)lB;

  for (int kt = 0; kt < KDIM; kt += 64) {
#pragma unroll
    for (int t = 0; t < 4; ++t) {
      int o = wv * 4096 + t * 1024 + lane * 16;   // byte offset in 16KB tile
      int row = o >> 7, cb = o & 127;             // 128B per row (64 bf16)
      GLDS(Ab + ((size_t)(m0 + row) * KDIM + kt) * 2 + cb, lAb + o);
      GLDS(Bb + ((size_t)(n0 + row) * KDIM + kt) * 2 + cb, lBb + o);
    }
    __syncthreads();

    short8 af[4][2], bfr[4][2];
#pragma unroll
    for (int i = 0; i < 4; ++i) {
#pragma unroll
      for (int kc = 0; kc < 2; ++kc) {
        af[i][kc]  = *(const short8*)(lAb + (wr * 64 + i * 16 + l15) * 128 + kc * 64 + l4 * 16);
        bfr[i][kc] = *(const short8*)(lBb + (wc * 64 + i * 16 + l15) * 128 + kc * 64 + l4 * 16);
      }
    }
#pragma unroll
    for (int i = 0; i < 4; ++i)
#pragma unroll
      for (int j = 0; j < 4; ++j)
#pragma unroll
        for (int kc = 0; kc < 2; ++kc)
          acc[i][j] = mfma16(af[i][kc], bfr[j][kc], acc[i][j]);
    __syncthreads();
  }

  // epilogue: D layout row=(l>>4)*4+r, col=l&15
#pragma unroll
  for (int i = 0; i < 4; ++i) {
#pragma unroll
    for (int j = 0; j < 4; ++j) {
#pragma unroll
      for (int r = 0; r < 4; ++r) {
        int grow = m0 + wr * 64 + i * 16 + l4 * 4 + r;
        int gcol = n0 + wc * 64 + j * 16 + l15;
        float v = acc[i][j][r];
        if (EPI == 0) {
          int b = grow >> 11, n = grow & (NSEQ - 1);
          int which = gcol >> 10, inner = gcol & 1023;
          int h = inner >> 6, dd = inner & 63;
          size_t off = ((size_t)(b * HEADS + h) * NSEQ + n) * DHEAD + dd;
          if (which == 0)
            q_out[off] = f2bf(v * QSCALE);
          else if (which == 1)
            k_out[off] = f2bf(v);
          else
            v_out[off] = f2bf(v);
        } else {
          outp[(size_t)grow * INNER + gcol] = v + bias[gcol];
        }
      }
    }
  }
}

// ---------------- flash attention: 1 wave per 32-row Q tile ----------------
// grid: 1D, NSEQ/32 * 32 blocks; bh = bid & 31 clusters each bh's q-tiles on
// one XCD (bid % 8 stable) so K/V stay hot in that XCD's L2.
__global__ __launch_bounds__(64) void attn_kernel(
    const ushort* __restrict__ q, const ushort* __restrict__ k,
    const ushort* __restrict__ vt, const int* __restrict__ lens,
    ushort* __restrict__ ctx) {
  __shared__ __align__(16) ushort lp[32 * 40];   // P tile, padded stride 40
  const int lane = threadIdx.x;
  const int l15 = lane & 15, l4 = lane >> 4;
  const int bid = blockIdx.x;
  const int bh = bid & 31, qt = bid >> 5;        // qt: 32-row tile index
  const int b = bh >> 4, h = bh & 15;
  const int len = lens[b];
  const ushort* qb  = q  + (size_t)bh * NSEQ * DHEAD;
  const ushort* kbp = k  + (size_t)bh * NSEQ * DHEAD;
  const ushort* vtb = vt + (size_t)bh * DHEAD * NSEQ;

  short8 qf[2][2];
#pragma unroll
  for (int mb = 0; mb < 2; ++mb) {
    int qrow = qt * 32 + mb * 16 + l15;
    qf[mb][0] = *(const short8*)&qb[qrow * DHEAD + l4 * 8];
    qf[mb][1] = *(const short8*)&qb[qrow * DHEAD + 32 + l4 * 8];
  }

  f32x4 zero = {0.f, 0.f, 0.f, 0.f};
  f32x4 O[2][4];
  float m[2][4], lsum[2][4];
#pragma unroll
  for (int mb = 0; mb < 2; ++mb) {
#pragma unroll
    for (int dc = 0; dc < 4; ++dc) O[mb][dc] = zero;
#pragma unroll
    for (int r = 0; r < 4; ++r) { m[mb][r] = -3.0e38f; lsum[mb][r] = 0.f; }
  }

  const int kbmax = qt;   // causal: keys up to qt*32+31
  for (int kb = 0; kb <= kbmax; ++kb) {
    // ---- QK^T ----
    f32x4 S[2][2];
#pragma unroll
    for (int mb = 0; mb < 2; ++mb) { S[mb][0] = zero; S[mb][1] = zero; }
#pragma unroll
    for (int cb = 0; cb < 2; ++cb) {
      int krow = kb * 32 + cb * 16 + l15;
      short8 kf0 = *(const short8*)&kbp[krow * DHEAD + l4 * 8];
      short8 kf1 = *(const short8*)&kbp[krow * DHEAD + 32 + l4 * 8];
#pragma unroll
      for (int mb = 0; mb < 2; ++mb) {
        S[mb][cb] = mfma16(qf[mb][0], kf0, S[mb][cb]);
        S[mb][cb] = mfma16(qf[mb][1], kf1, S[mb][cb]);
      }
    }

    // ---- prefetch V fragments (independent of softmax; hides L2 latency) ----
    short8 vf[4];
#pragma unroll
    for (int dc = 0; dc < 4; ++dc)
      vf[dc] = *(const short8*)&vtb[(size_t)(dc * 16 + l15) * NSEQ + kb * 32 + l4 * 8];

    // ---- online softmax (exp2 domain; q pre-scaled by SCALE*log2e) ----
    int j0 = kb * 32 + l15, j1 = j0 + 16;
    float sc[2][4];
#pragma unroll
    for (int mb = 0; mb < 2; ++mb) {
#pragma unroll
      for (int r = 0; r < 4; ++r) {
        int rowg = qt * 32 + mb * 16 + l4 * 4 + r;
        float s0 = S[mb][0][r], s1 = S[mb][1][r];
        bool v0 = (j0 <= rowg) && (j0 < len);
        bool v1 = (j1 <= rowg) && (j1 < len);
        s0 = v0 ? s0 : -3.0e38f;
        s1 = v1 ? s1 : -3.0e38f;
        float t = fmaxf(s0, s1);
        t = fmaxf(t, __shfl_xor(t, 1));
        t = fmaxf(t, __shfl_xor(t, 2));
        t = fmaxf(t, __shfl_xor(t, 4));
        t = fmaxf(t, __shfl_xor(t, 8));
        float mn = fmaxf(m[mb][r], t);
        float scale = exp2f(m[mb][r] - mn);
        float p0 = v0 ? exp2f(s0 - mn) : 0.f;
        float p1 = v1 ? exp2f(s1 - mn) : 0.f;
        float rs = p0 + p1;
        rs += __shfl_xor(rs, 1);
        rs += __shfl_xor(rs, 2);
        rs += __shfl_xor(rs, 4);
        rs += __shfl_xor(rs, 8);
        lsum[mb][r] = lsum[mb][r] * scale + rs;
        m[mb][r] = mn; sc[mb][r] = scale;
        int prow = mb * 16 + l4 * 4 + r;
        lp[prow * 40 + l15]      = f2bf(p0);
        lp[prow * 40 + 16 + l15] = f2bf(p1);
      }
    }
#pragma unroll
    for (int mb = 0; mb < 2; ++mb)
#pragma unroll
      for (int dc = 0; dc < 4; ++dc) {
        O[mb][dc][0] *= sc[mb][0]; O[mb][dc][1] *= sc[mb][1];
        O[mb][dc][2] *= sc[mb][2]; O[mb][dc][3] *= sc[mb][3];
      }
    __syncthreads();

    // ---- PV ----
#pragma unroll
    for (int mb = 0; mb < 2; ++mb) {
      short8 pf = *(const short8*)&lp[(mb * 16 + l15) * 40 + l4 * 8];
#pragma unroll
      for (int dc = 0; dc < 4; ++dc)
        O[mb][dc] = mfma16(pf, vf[dc], O[mb][dc]);
    }
    __syncthreads();
  }

  // ---- epilogue ----
#pragma unroll
  for (int mb = 0; mb < 2; ++mb) {
#pragma unroll
    for (int r = 0; r < 4; ++r) {
      int n = qt * 32 + mb * 16 + l4 * 4 + r;
      float inv = 1.0f / lsum[mb][r];
      size_t rowoff = ((size_t)(b * NSEQ + n)) * INNER + h * DHEAD;
#pragma unroll
      for (int dc = 0; dc < 4; ++dc)
        ctx[rowoff + dc * 16 + l15] = f2bf(O[mb][dc][r] * inv);
    }
  }
}

// ---------------- launcher ----------------
extern "C" void kernel_launch(void* const* d_in, const int* in_sizes, int n_in,
                              void* d_out, int out_size, void* d_ws, size_t ws_size,
                              hipStream_t stream) {
  const float* x    = (const float*)d_in[0];
  const int*   mask = (const int*)d_in[1];
  const float* Wqkv = (const float*)d_in[2];
  const float* Wout = (const float*)d_in[3];
  const float* bias = (const float*)d_in[4];
  float* out = (float*)d_out;

  const size_t QKV_ELEMS = (size_t)BATCH * HEADS * NSEQ * DHEAD;  // 4.19M each

  ushort* ws = (ushort*)d_ws;
  ushort* x_bf  = ws;                                  // 4096*1024 (reused as vt later)
  ushort* wq_t  = x_bf  + (size_t)BNROWS * DMODEL;     // 3072*1024
  ushort* wo_t  = wq_t  + (size_t)NCOL * KDIM;         // 1024*1024
  ushort* q_bf  = wo_t  + (size_t)INNER * KDIM;
  ushort* k_bf  = q_bf  + QKV_ELEMS;
  ushort* v_bf  = k_bf  + QKV_ELEMS;
  ushort* ctx   = v_bf  + QKV_ELEMS;                   // 4096*1024
  int* lens = (int*)(ctx + (size_t)BNROWS * INNER);
  ushort* vt_bf = x_bf;   // alias: x_bf dead after QKV GEMM, same size as V

  lens_kernel<<<dim3(BATCH), dim3(256), 0, stream>>>(mask, lens);
  cast_bf16_kernel<<<dim3((BNROWS * DMODEL / 8 + 255) / 256), dim3(256), 0, stream>>>(
      x, x_bf, BNROWS * DMODEL / 8);
  transpose_bf16_kernel<<<dim3(NCOL / 32, KDIM / 32), dim3(32, 8), 0, stream>>>(
      Wqkv, wq_t, KDIM, NCOL);
  transpose_bf16_kernel<<<dim3(INNER / 32, KDIM / 32), dim3(32, 8), 0, stream>>>(
      Wout, wo_t, KDIM, INNER);

  gemm_bt_kernel<0><<<dim3(BNROWS / 128, NCOL / 128), dim3(256), 0, stream>>>(
      x_bf, wq_t, q_bf, k_bf, v_bf, nullptr, nullptr);

  vtrans_kernel<<<dim3(DHEAD / 32, NSEQ / 32, BATCH * HEADS), dim3(32, 8), 0, stream>>>(
      v_bf, vt_bf);

  attn_kernel<<<dim3((NSEQ / 32) * BATCH * HEADS), dim3(64), 0, stream>>>(
      q_bf, k_bf, vt_bf, lens, ctx);

  gemm_bt_kernel<1><<<dim3(BNROWS / 128, INNER / 128), dim3(256), 0, stream>>>(
      ctx, wo_t, nullptr, nullptr, nullptr, bias, out);
}

// Round 4
// 237.436 us; speedup vs baseline: 1.3436x; 1.3436x over previous
//
#include <hip/hip_runtime.h>

// ---------------- constants ----------------
#define BATCH   2
#define NSEQ    2048
#define DMODEL  1024
#define HEADS   16
#define DHEAD   64
#define INNER   1024      // HEADS*DHEAD
#define NCOL    3072      // 3*INNER
#define BNROWS  4096      // BATCH*NSEQ
#define KDIM    1024      // contraction dim for both GEMMs

typedef unsigned short ushort;
typedef unsigned int   uint;
typedef __attribute__((ext_vector_type(8)))  short  short8;
typedef __attribute__((ext_vector_type(4)))  float  f32x4;
typedef __attribute__((ext_vector_type(16))) float  f32x16;
typedef __attribute__((ext_vector_type(8)))  ushort ushort8;
typedef __attribute__((ext_vector_type(4)))  float  f4v;
typedef __attribute__((ext_vector_type(4)))  uint   uint4v;

// SCALE * log2(e) so softmax can use exp2 directly
#define QSCALE 0.1803368801111204f   // 64^-0.5 * 1.4426950408889634

__device__ __forceinline__ ushort f2bf(float f) {
  uint u = __builtin_bit_cast(uint, f);
  u += 0x7fffu + ((u >> 16) & 1u);   // RNE
  return (ushort)(u >> 16);
}
__device__ __forceinline__ uint pkbf(float a, float b) {
  return (uint)f2bf(a) | ((uint)f2bf(b) << 16);
}

__device__ __forceinline__ f32x4 mfma16(short8 a, short8 b, f32x4 c) {
  return __builtin_amdgcn_mfma_f32_16x16x32_bf16(a, b, c, 0, 0, 0);
}
__device__ __forceinline__ f32x16 mfma32(short8 a, short8 b, f32x16 c) {
  return __builtin_amdgcn_mfma_f32_32x32x16_bf16(a, b, c, 0, 0, 0);
}

#define GLDS(gp, lp) __builtin_amdgcn_global_load_lds( \
    (const __attribute__((address_space(1))) void*)(gp), \
    (__attribute__((address_space(3))) void*)(lp), 16, 0, 0)

// ---------------- lengths from mask (int32 0/1) ----------------
__global__ __launch_bounds__(256) void lens_kernel(const int* __restrict__ mask,
                                                   int* __restrict__ lens) {
  __shared__ int sm[256];
  int b = blockIdx.x, t = threadIdx.x;
  int s = 0;
  for (int i = t; i < NSEQ; i += 256) s += (mask[b * NSEQ + i] != 0);
  sm[t] = s;
  __syncthreads();
  for (int off = 128; off > 0; off >>= 1) {
    if (t < off) sm[t] += sm[t + off];
    __syncthreads();
  }
  if (t == 0) lens[b] = sm[0];
}

// ---------------- fp32 -> bf16 cast (vectorized) ----------------
__global__ __launch_bounds__(256) void cast_bf16_kernel(const float* __restrict__ x,
                                                        ushort* __restrict__ y, int n8) {
  int i = blockIdx.x * 256 + threadIdx.x;
  if (i >= n8) return;
  const f4v* xv = (const f4v*)x;
  f4v a = xv[(size_t)i * 2], b = xv[(size_t)i * 2 + 1];
  ushort8 o;
  o[0] = f2bf(a[0]); o[1] = f2bf(a[1]); o[2] = f2bf(a[2]); o[3] = f2bf(a[3]);
  o[4] = f2bf(b[0]); o[5] = f2bf(b[1]); o[6] = f2bf(b[2]); o[7] = f2bf(b[3]);
  ((ushort8*)y)[i] = o;
}

// ---------------- fp32 (K,C) -> bf16 transposed (C,K) ----------------
__global__ __launch_bounds__(256) void transpose_bf16_kernel(const float* __restrict__ W,
                                                             ushort* __restrict__ Wt,
                                                             int K, int C) {
  __shared__ float tile[32][33];
  int c0 = blockIdx.x * 32, k0 = blockIdx.y * 32;
  int tx = threadIdx.x, ty = threadIdx.y;   // (32,8)
#pragma unroll
  for (int i = 0; i < 4; ++i)
    tile[ty + i * 8][tx] = W[(size_t)(k0 + ty + i * 8) * C + c0 + tx];
  __syncthreads();
#pragma unroll
  for (int i = 0; i < 4; ++i)
    Wt[(size_t)(c0 + ty + i * 8) * K + k0 + tx] = f2bf(tile[tx][ty + i * 8]);
}

// ---------------- bf16 (bh, n, d) -> (bh, d, n) transpose for V ----------------
__global__ __launch_bounds__(256) void vtrans_kernel(const ushort* __restrict__ v,
                                                     ushort* __restrict__ vt) {
  __shared__ ushort t[32][34];
  int d0 = blockIdx.x * 32, n0 = blockIdx.y * 32, bh = blockIdx.z;
  const ushort* vb  = v  + (size_t)bh * NSEQ * DHEAD;
  ushort*       vtb = vt + (size_t)bh * NSEQ * DHEAD;
  int tx = threadIdx.x, ty = threadIdx.y;   // (32,8)
#pragma unroll
  for (int i = 0; i < 4; ++i)
    t[ty + i * 8][tx] = vb[(size_t)(n0 + ty + i * 8) * DHEAD + d0 + tx];
  __syncthreads();
#pragma unroll
  for (int i = 0; i < 4; ++i)
    vtb[(size_t)(d0 + ty + i * 8) * NSEQ + n0 + tx] = t[tx][ty + i * 8];
}

// ---------------- m97-style bf16 GEMM, C = A(M,K) @ Bt(N,K)^T ----------------
template <int EPI>
__global__ __launch_bounds__(256) void gemm_bt_kernel(
    const ushort* __restrict__ A, const ushort* __restrict__ Bt,
    ushort* __restrict__ q_out, ushort* __restrict__ k_out, ushort* __restrict__ v_out,
    const float* __restrict__ bias, float* __restrict__ outp) {
  __shared__ __align__(16) ushort lA[128 * 64];
  __shared__ __align__(16) ushort lB[128 * 64];
  const int tid = threadIdx.x;
  const int wv = tid >> 6, lane = tid & 63;
  const int wr = wv >> 1, wc = wv & 1;
  const int m0 = blockIdx.x * 128, n0 = blockIdx.y * 128;
  const int l15 = lane & 15, l4 = lane >> 4;

  f32x4 zero = {0.f, 0.f, 0.f, 0.f};
  f32x4 acc[4][4];
#pragma unroll
  for (int i = 0; i < 4; ++i)
#pragma unroll
    for (int j = 0; j < 4; ++j) acc[i][j] = zero;

  const char* Ab  = (const char*)A;
  const char* Bb  = (const char*)Bt;
  char* lAb = (char*)lA;
  char* lBb = (char*)lB;

  for (int kt = 0; kt < KDIM; kt += 64) {
#pragma unroll
    for (int t = 0; t < 4; ++t) {
      int o = wv * 4096 + t * 1024 + lane * 16;
      int row = o >> 7, cb = o & 127;
      GLDS(Ab + ((size_t)(m0 + row) * KDIM + kt) * 2 + cb, lAb + o);
      GLDS(Bb + ((size_t)(n0 + row) * KDIM + kt) * 2 + cb, lBb + o);
    }
    __syncthreads();

    short8 af[4][2], bfr[4][2];
#pragma unroll
    for (int i = 0; i < 4; ++i) {
#pragma unroll
      for (int kc = 0; kc < 2; ++kc) {
        af[i][kc]  = *(const short8*)(lAb + (wr * 64 + i * 16 + l15) * 128 + kc * 64 + l4 * 16);
        bfr[i][kc] = *(const short8*)(lBb + (wc * 64 + i * 16 + l15) * 128 + kc * 64 + l4 * 16);
      }
    }
#pragma unroll
    for (int i = 0; i < 4; ++i)
#pragma unroll
      for (int j = 0; j < 4; ++j)
#pragma unroll
        for (int kc = 0; kc < 2; ++kc)
          acc[i][j] = mfma16(af[i][kc], bfr[j][kc], acc[i][j]);
    __syncthreads();
  }

#pragma unroll
  for (int i = 0; i < 4; ++i) {
#pragma unroll
    for (int j = 0; j < 4; ++j) {
#pragma unroll
      for (int r = 0; r < 4; ++r) {
        int grow = m0 + wr * 64 + i * 16 + l4 * 4 + r;
        int gcol = n0 + wc * 64 + j * 16 + l15;
        float v = acc[i][j][r];
        if (EPI == 0) {
          int b = grow >> 11, n = grow & (NSEQ - 1);
          int which = gcol >> 10, inner = gcol & 1023;
          int h = inner >> 6, dd = inner & 63;
          size_t off = ((size_t)(b * HEADS + h) * NSEQ + n) * DHEAD + dd;
          if (which == 0)
            q_out[off] = f2bf(v * QSCALE);
          else if (which == 1)
            k_out[off] = f2bf(v);
          else
            v_out[off] = f2bf(v);
        } else {
          outp[(size_t)grow * INNER + gcol] = v + bias[gcol];
        }
      }
    }
  }
}

// ---------------- flash attention: swapped-QK^T, in-register softmax ----------------
// 1 wave per 32-row Q tile; S^T = mfma32(K, Q): lane owns q-row (lane&31) and 16
// key-slots (reg) -> row reduce = in-register tree + ONE shfl_xor(32).
// PV as O^T = mfma32(V^T, P^T): O^T col = lane's q-row -> lane-local rescale.
__global__ __launch_bounds__(64) void attn_kernel(
    const ushort* __restrict__ q, const ushort* __restrict__ k,
    const ushort* __restrict__ vt, const int* __restrict__ lens,
    ushort* __restrict__ ctx) {
  const int lane = threadIdx.x;
  const int l31 = lane & 31, hi = lane >> 5;
  const int bid = blockIdx.x;
  const int bh = bid & 31, qt = bid >> 5;        // bh-major in low bits: XCD/L2 clustering
  const int b = bh >> 4, h = bh & 15;
  const int len = lens[b];
  const ushort* qb  = q  + (size_t)bh * NSEQ * DHEAD;
  const ushort* kbp = k  + (size_t)bh * NSEQ * DHEAD;
  const ushort* vtb = vt + (size_t)bh * DHEAD * NSEQ;

  const int qglob = qt * 32 + l31;
  const int qcap  = min(qglob, len - 1);         // valid keys: j <= qcap

  // Q fragments (B-operand of S^T mfma): q-row = l31, d-chunk = dk*16 + hi*8
  short8 qf[4];
#pragma unroll
  for (int dk = 0; dk < 4; ++dk)
    qf[dk] = *(const short8*)&qb[(size_t)(qt * 32 + l31) * DHEAD + dk * 16 + hi * 8];

  f32x16 Ot[2];
#pragma unroll
  for (int d0b = 0; d0b < 2; ++d0b)
#pragma unroll
    for (int r = 0; r < 16; ++r) Ot[d0b][r] = 0.f;
  float mrow = -3.0e38f, lsum = 0.f;

  const int kbend = min(qt, (len - 1) >> 5);

  // prefetch K tile 0 (A-operand: key-row = l31, d-chunk = dk*16 + hi*8)
  short8 kf[4], kn[4];
#pragma unroll
  for (int dk = 0; dk < 4; ++dk)
    kf[dk] = *(const short8*)&kbp[(size_t)l31 * DHEAD + dk * 16 + hi * 8];

  for (int kb = 0; kb <= kbend; ++kb) {
    // ---- S^T = K . Q^T ----
    f32x16 S;
#pragma unroll
    for (int r = 0; r < 16; ++r) S[r] = 0.f;
#pragma unroll
    for (int dk = 0; dk < 4; ++dk) S = mfma32(kf[dk], qf[dk], S);

    // ---- V fragments (A-operand of O^T): d = d0b*32 + l31, n-chunk ks*16+hi*8 ----
    short8 vf[2][2];
#pragma unroll
    for (int d0b = 0; d0b < 2; ++d0b)
#pragma unroll
      for (int ks = 0; ks < 2; ++ks)
        vf[d0b][ks] = *(const short8*)&vtb[(size_t)(d0b * 32 + l31) * NSEQ +
                                           kb * 32 + ks * 16 + hi * 8];

    // ---- prefetch next K tile (latency hidden under softmax) ----
    {
      int kread = min(kb + 1, kbend);
#pragma unroll
      for (int dk = 0; dk < 4; ++dk)
        kn[dk] = *(const short8*)&kbp[(size_t)(kread * 32 + l31) * DHEAD + dk * 16 + hi * 8];
    }

    // ---- mask (wave-uniform fast path skips it) ----
    bool fast = (kb < qt) && (kb * 32 + 31 < len);
    if (!fast) {
      int base = kb * 32 + 4 * hi;
#pragma unroll
      for (int r = 0; r < 16; ++r) {
        int c = (r & 3) + 8 * (r >> 2);
        if (base + c > qcap) S[r] = -3.0e38f;
      }
    }

    // ---- row max: in-register tree + one cross-half shfl ----
    float t0 = fmaxf(S[0], S[1]),  t1 = fmaxf(S[2], S[3]);
    float t2 = fmaxf(S[4], S[5]),  t3 = fmaxf(S[6], S[7]);
    float t4 = fmaxf(S[8], S[9]),  t5 = fmaxf(S[10], S[11]);
    float t6 = fmaxf(S[12], S[13]), t7 = fmaxf(S[14], S[15]);
    t0 = fmaxf(t0, t1); t2 = fmaxf(t2, t3); t4 = fmaxf(t4, t5); t6 = fmaxf(t6, t7);
    float pm = fmaxf(fmaxf(t0, t2), fmaxf(t4, t6));
    pm = fmaxf(pm, __shfl_xor(pm, 32));

    // ---- defer-max (T13, THR=8 in exp2 domain) ----
    if (!__all(pm <= mrow + 8.0f)) {
      float mnew = fmaxf(mrow, pm);
      float scale = exp2f(mrow - mnew);
      lsum *= scale;
#pragma unroll
      for (int d0b = 0; d0b < 2; ++d0b)
#pragma unroll
        for (int r = 0; r < 16; ++r) Ot[d0b][r] *= scale;
      mrow = mnew;
    }

    // ---- p = exp2(S - m); row sum ----
    float p[16];
#pragma unroll
    for (int r = 0; r < 16; ++r) p[r] = exp2f(S[r] - mrow);
    float s0 = (p[0] + p[1]) + (p[2] + p[3]);
    float s1 = (p[4] + p[5]) + (p[6] + p[7]);
    float s2 = (p[8] + p[9]) + (p[10] + p[11]);
    float s3 = (p[12] + p[13]) + (p[14] + p[15]);
    float rs = (s0 + s1) + (s2 + s3);
    rs += __shfl_xor(rs, 32);
    lsum += rs;

    // ---- pack P to bf16 pairs; exchange halves to build P^T B-fragments ----
    uint Pw[8], Xw[8];
#pragma unroll
    for (int i = 0; i < 8; ++i) Pw[i] = pkbf(p[2 * i], p[2 * i + 1]);
#pragma unroll
    for (int i = 0; i < 8; ++i) Xw[i] = __shfl_xor(Pw[i], 32);
    uint4v bw0 = { hi ? Xw[2] : Pw[0], hi ? Xw[3] : Pw[1],
                   hi ? Pw[2] : Xw[0], hi ? Pw[3] : Xw[1] };
    uint4v bw1 = { hi ? Xw[6] : Pw[4], hi ? Xw[7] : Pw[5],
                   hi ? Pw[6] : Xw[4], hi ? Pw[7] : Xw[5] };
    short8 pb0 = __builtin_bit_cast(short8, bw0);
    short8 pb1 = __builtin_bit_cast(short8, bw1);

    // ---- O^T += V^T . P^T ----
#pragma unroll
    for (int d0b = 0; d0b < 2; ++d0b) {
      Ot[d0b] = mfma32(vf[d0b][0], pb0, Ot[d0b]);
      Ot[d0b] = mfma32(vf[d0b][1], pb1, Ot[d0b]);
    }

#pragma unroll
    for (int dk = 0; dk < 4; ++dk) kf[dk] = kn[dk];
  }

  // ---- epilogue: O^T col = lane's q-row; rows are d (pairs contiguous) ----
  float inv = 1.0f / lsum;
  size_t rowbase = ((size_t)(b * NSEQ) + qglob) * INNER + h * DHEAD;
#pragma unroll
  for (int d0b = 0; d0b < 2; ++d0b) {
#pragma unroll
    for (int i = 0; i < 8; ++i) {
      int d = 2 * (i & 1) + 8 * (i >> 1) + 4 * hi;   // crow(2i,hi); pair (d, d+1)
      uint w = pkbf(Ot[d0b][2 * i] * inv, Ot[d0b][2 * i + 1] * inv);
      *(uint*)&ctx[rowbase + d0b * 32 + d] = w;
    }
  }
}

// ---------------- launcher ----------------
extern "C" void kernel_launch(void* const* d_in, const int* in_sizes, int n_in,
                              void* d_out, int out_size, void* d_ws, size_t ws_size,
                              hipStream_t stream) {
  const float* x    = (const float*)d_in[0];
  const int*   mask = (const int*)d_in[1];
  const float* Wqkv = (const float*)d_in[2];
  const float* Wout = (const float*)d_in[3];
  const float* bias = (const float*)d_in[4];
  float* out = (float*)d_out;

  const size_t QKV_ELEMS = (size_t)BATCH * HEADS * NSEQ * DHEAD;

  ushort* ws = (ushort*)d_ws;
  ushort* x_bf  = ws;
  ushort* wq_t  = x_bf  + (size_t)BNROWS * DMODEL;
  ushort* wo_t  = wq_t  + (size_t)NCOL * KDIM;
  ushort* q_bf  = wo_t  + (size_t)INNER * KDIM;
  ushort* k_bf  = q_bf  + QKV_ELEMS;
  ushort* v_bf  = k_bf  + QKV_ELEMS;
  ushort* ctx   = v_bf  + QKV_ELEMS;
  int* lens = (int*)(ctx + (size_t)BNROWS * INNER);
  ushort* vt_bf = x_bf;   // alias: x_bf dead after QKV GEMM

  lens_kernel<<<dim3(BATCH), dim3(256), 0, stream>>>(mask, lens);
  cast_bf16_kernel<<<dim3((BNROWS * DMODEL / 8 + 255) / 256), dim3(256), 0, stream>>>(
      x, x_bf, BNROWS * DMODEL / 8);
  transpose_bf16_kernel<<<dim3(NCOL / 32, KDIM / 32), dim3(32, 8), 0, stream>>>(
      Wqkv, wq_t, KDIM, NCOL);
  transpose_bf16_kernel<<<dim3(INNER / 32, KDIM / 32), dim3(32, 8), 0, stream>>>(
      Wout, wo_t, KDIM, INNER);

  gemm_bt_kernel<0><<<dim3(BNROWS / 128, NCOL / 128), dim3(256), 0, stream>>>(
      x_bf, wq_t, q_bf, k_bf, v_bf, nullptr, nullptr);

  vtrans_kernel<<<dim3(DHEAD / 32, NSEQ / 32, BATCH * HEADS), dim3(32, 8), 0, stream>>>(
      v_bf, vt_bf);

  attn_kernel<<<dim3((NSEQ / 32) * BATCH * HEADS), dim3(64), 0, stream>>>(
      q_bf, k_bf, vt_bf, lens, ctx);

  gemm_bt_kernel<1><<<dim3(BNROWS / 128, INNER / 128), dim3(256), 0, stream>>>(
      ctx, wo_t, nullptr, nullptr, nullptr, bias, out);
}